// Round 9
// baseline (335.733 us; speedup 1.0000x reference)
//
#include <hip/hip_runtime.h>
#include <cstddef>
#include <cstdint>

// Problem constants
constexpr int kB   = 4;
constexpr int kT   = 2048;
constexpr int kD   = 1024;   // d_model
constexpr int kH   = 16;     // heads
constexpr int kDh  = 64;     // head dim
constexpr int kBT  = kB * kT;          // 8192 rows
constexpr int kQKVN = 3 * kD;          // 3072

typedef _Float16 f16x8 __attribute__((ext_vector_type(8)));
typedef _Float16 f16x4 __attribute__((ext_vector_type(4)));
typedef _Float16 f16x2 __attribute__((ext_vector_type(2)));
typedef float    f32x4  __attribute__((ext_vector_type(4)));
typedef float    f32x16 __attribute__((ext_vector_type(16)));

#define GLD16(g, l)                                                        \
    __builtin_amdgcn_global_load_lds(                                      \
        (const __attribute__((address_space(1))) void*)(g),                \
        (__attribute__((address_space(3))) void*)(l), 16, 0, 0)

static __device__ __forceinline__ int pkrtz_i(float a, float b) {
    auto t = __builtin_amdgcn_cvt_pkrtz(a, b);   // v_cvt_pkrtz_f16_f32
    return *reinterpret_cast<int*>(&t);
}

// ---------------------------------------------------------------------------
// all fp32->fp16 casts + bias concat in one dispatch
// ---------------------------------------------------------------------------
__global__ __launch_bounds__(256) void cast_all(const float* __restrict__ x,
                                                const float* __restrict__ Wq,
                                                const float* __restrict__ Wk,
                                                const float* __restrict__ Wv,
                                                const float* __restrict__ Wo,
                                                const float* __restrict__ bq,
                                                const float* __restrict__ bk,
                                                const float* __restrict__ bv,
                                                _Float16* __restrict__ Xh,
                                                _Float16* __restrict__ Wqkvh,
                                                _Float16* __restrict__ Woh,
                                                float* __restrict__ bqkv) {
    const int i = blockIdx.x * 256 + threadIdx.x;
    if (i >= 3145728) {                 // bias concat: 768 float4 groups
        const int j = i - 3145728;
        if (j < 768) {
            const float* bs = (j < 256) ? bq : (j < 512 ? bk : bv);
            const int jo = j & 255;
            reinterpret_cast<float4*>(bqkv)[j] =
                reinterpret_cast<const float4*>(bs)[jo];
        }
        return;
    }
    const float* src; _Float16* dst; int off;
    if (i < 2097152)      { src = x;  dst = Xh;              off = i; }
    else if (i < 2359296) { src = Wq; dst = Wqkvh;           off = i - 2097152; }
    else if (i < 2621440) { src = Wk; dst = Wqkvh + 1048576; off = i - 2359296; }
    else if (i < 2883584) { src = Wv; dst = Wqkvh + 2097152; off = i - 2621440; }
    else                  { src = Wo; dst = Woh;             off = i - 2883584; }
    const float4 v = reinterpret_cast<const float4*>(src)[off];
    f16x4 o = { (_Float16)v.x, (_Float16)v.y, (_Float16)v.z, (_Float16)v.w };
    reinterpret_cast<f16x4*>(dst)[off] = o;
}

// ---------------------------------------------------------------------------
// fp16 MFMA GEMM: C[M,N] = A[M,K] @ B[N,K]^T + bias
// BK=64 staged as two 32-K chunks in separate LDS regions (GLD16-compatible).
// 1D XCD-swizzled grid: id = nlo + 8*m + 512*ngrp, n = ngrp*8 + nlo -> all
// m-blocks sharing one n-block's 256 KB B-panel land on the same XCD under
// round-robin dispatch, so the B-panel stays L2-resident there.
// DO_ROPE: QKV projection applies RoPE in the epilogue to cols<2048
// (pair partner is lane^1) and pre-scales Q by log2(e)/8.
// ---------------------------------------------------------------------------
template <typename OUT_T, bool DO_ROPE>
__global__ __launch_bounds__(256) void gemm_f16(const _Float16* __restrict__ A,
                                                const _Float16* __restrict__ B,
                                                const float* __restrict__ bias,
                                                OUT_T* __restrict__ C,
                                                int M, int N, int K) {
    constexpr int BK = 64;
    __shared__ _Float16 As[128 * BK];   // [ko][128][32] chunked
    __shared__ _Float16 Bs[128 * BK];

    const int tid  = threadIdx.x;
    const int wave = tid >> 6;
    const int lane = tid & 63;
    const int quad = lane >> 4;
    const int r16  = lane & 15;

    // XCD-locality swizzled decode
    const int id = blockIdx.x;
    const int m0 = ((id >> 3) & 63) * 128;
    const int n0 = (((id >> 9) << 3) + (id & 7)) * 128;

    const int srow = lane >> 2;
    const int scol = (lane & 3) * 8;
    const _Float16* Ag0 = A + (size_t)(m0 + wave * 16 + srow) * K + scol;
    const _Float16* Ag1 = A + (size_t)(m0 + 64 + wave * 16 + srow) * K + scol;
    const _Float16* Bg0 = B + (size_t)(n0 + wave * 16 + srow) * K + scol;
    const _Float16* Bg1 = B + (size_t)(n0 + 64 + wave * 16 + srow) * K + scol;
    _Float16* Al0 = &As[(size_t)wave * 512];
    _Float16* Al1 = &As[(size_t)(wave + 4) * 512];
    _Float16* Bl0 = &Bs[(size_t)wave * 512];
    _Float16* Bl1 = &Bs[(size_t)(wave + 4) * 512];

    const int wm = (wave & 1) * 64;
    const int wn = (wave >> 1) * 64;

    f32x4 acc[4][4] = {};

    for (int k0 = 0; k0 < K; k0 += BK) {
        GLD16(Ag0 + k0,      Al0);
        GLD16(Ag1 + k0,      Al1);
        GLD16(Ag0 + k0 + 32, Al0 + 4096);
        GLD16(Ag1 + k0 + 32, Al1 + 4096);
        GLD16(Bg0 + k0,      Bl0);
        GLD16(Bg1 + k0,      Bl1);
        GLD16(Bg0 + k0 + 32, Bl0 + 4096);
        GLD16(Bg1 + k0 + 32, Bl1 + 4096);
        __syncthreads();

        #pragma unroll
        for (int ko = 0; ko < 2; ++ko) {
            f16x8 a[4], bf[4];
            #pragma unroll
            for (int mi = 0; mi < 4; ++mi)
                a[mi] = *reinterpret_cast<const f16x8*>(
                    &As[ko * 4096 + (wm + mi * 16 + r16) * 32 + quad * 8]);
            #pragma unroll
            for (int ni = 0; ni < 4; ++ni)
                bf[ni] = *reinterpret_cast<const f16x8*>(
                    &Bs[ko * 4096 + (wn + ni * 16 + r16) * 32 + quad * 8]);
            #pragma unroll
            for (int mi = 0; mi < 4; ++mi)
                #pragma unroll
                for (int ni = 0; ni < 4; ++ni)
                    acc[mi][ni] = __builtin_amdgcn_mfma_f32_16x16x32_f16(a[mi], bf[ni], acc[mi][ni], 0, 0, 0);
        }
        __syncthreads();
    }

    #pragma unroll
    for (int mi = 0; mi < 4; ++mi) {
        #pragma unroll
        for (int ni = 0; ni < 4; ++ni) {
            const int col = n0 + wn + ni * 16 + r16;
            const float bv = bias[col];
            #pragma unroll
            for (int r = 0; r < 4; ++r) {
                const int row = m0 + wm + mi * 16 + quad * 4 + r;
                float v = acc[mi][ni][r] + bv;
                if constexpr (DO_ROPE) {
                    // pair partner (col^1) lives in lane^1, same (mi,ni,r)
                    const float vx = __shfl_xor(v, 1);
                    if (col < 2048) {
                        const int t = row & (kT - 1);
                        const int p = (col & 63) >> 1;
                        const float rev = (float)t * ((float)p *
                            (1.0e-4f * 0.15915494309189535f));
                        const float s = __builtin_amdgcn_sinf(rev);
                        const float c = __builtin_amdgcn_cosf(rev);
                        const float sgn = (r16 & 1) ? s : -s;  // even: -s*partner
                        v = v * c + vx * sgn;
                        if (col < 1024) v *= 0.18033688011112443f;  // log2e/8
                    }
                }
                C[(size_t)row * N + col] = (OUT_T)v;
            }
        }
    }
}

// ---------------------------------------------------------------------------
// V transpose: QKV[,2048+h*64+d] (rows t) -> Vt[bh][d][t]
// ---------------------------------------------------------------------------
__global__ __launch_bounds__(256) void transpose_v(const _Float16* __restrict__ QKV,
                                                   _Float16* __restrict__ Vt) {
    const int bh = blockIdx.y;
    const int t0 = blockIdx.x * 64;
    const int b = bh >> 4, h = bh & 15;
    __shared__ _Float16 T[64 * 72];

    const int tid = threadIdx.x;
    const int r   = tid >> 2;
    const int c0  = (tid & 3) * 16;
    const _Float16* src = QKV + (size_t)(b * kT + t0 + r) * kQKVN + 2048 + h * 64 + c0;
    *reinterpret_cast<f16x8*>(&T[r * 72 + c0])     = *reinterpret_cast<const f16x8*>(src);
    *reinterpret_cast<f16x8*>(&T[r * 72 + c0 + 8]) = *reinterpret_cast<const f16x8*>(src + 8);
    __syncthreads();

    const int d = tid >> 2, tc0 = (tid & 3) * 16;
    f16x8 o0, o1;
    #pragma unroll
    for (int j = 0; j < 8; ++j) o0[j] = T[(tc0 + j) * 72 + d];
    #pragma unroll
    for (int j = 0; j < 8; ++j) o1[j] = T[(tc0 + 8 + j) * 72 + d];
    _Float16* dst = Vt + ((size_t)bh * 64 + d) * kT + t0 + tc0;
    *reinterpret_cast<f16x8*>(dst)     = o0;
    *reinterpret_cast<f16x8*>(dst + 8) = o1;
}

// ---------------------------------------------------------------------------
// Flash attention, split-K (S=4), XCD-locality swizzled 1D grid (2048 blocks):
//   id = qt*8 + (flat&7) + (flat>>3)*64, flat = bh*4+sp -> the 8 q-tile blocks
//   sharing one (bh,sp)'s 128 KB of K/V get IDs congruent mod 8 -> same XCD
//   -> K/V staging re-reads hit that XCD's L2 (FETCH 164->49 MB, R8-verified).
// Plain pointer-incremented staging (no register prefetch: R8 showed the
//   VGPR cost (96->144) halves occupancy and cancels the latency win).
// Max-free softmax => splits merge LINEARLY (O = sum O_s, l = sum l_s).
// P C->A transform via asymmetric shfl_xor(32) quad exchange.
// C/D layout: col = lane&31, row = (reg&3) + 8*(reg>>2) + 4*(lane>>5).
// A/B frag: row/col = lane&31, k = (lane>>5)*8 + j.  [HW-verified R3-R8]
// ---------------------------------------------------------------------------
__global__ __launch_bounds__(256) void attn_mfma(const _Float16* __restrict__ QKV,
                                                 const _Float16* __restrict__ Vt,
                                                 _Float16* __restrict__ Op0,
                                                 _Float16* __restrict__ Op1,
                                                 _Float16* __restrict__ Op2,
                                                 _Float16* __restrict__ Op3,
                                                 float* __restrict__ lp) {
    constexpr int LDK = 72, LDV = 136;
    __shared__ _Float16 Ks[128 * LDK];   // [key 0..128)[d 0..64)
    __shared__ _Float16 Vts[64 * LDV];   // [d 0..64)[key 0..128)

    // swizzled decode
    const int id   = blockIdx.x;              // 0..2047
    const int qt   = (id >> 3) & 7;
    const int flat = ((id >> 6) << 3) + (id & 7);   // 0..255
    const int bh = flat >> 2;
    const int sp = flat & 3;
    const int b = bh >> 4, h = bh & 15;
    const int q0 = qt * 256;

    _Float16* __restrict__ Opart;
    int ostride;
    if (sp == 0)      { Opart = Op0; ostride = 1024; }
    else if (sp == 1) { Opart = Op1; ostride = 1024; }
    else if (sp == 2) { Opart = Op2; ostride = 3072; }
    else              { Opart = Op3; ostride = 1024; }
    float* __restrict__ lpart = lp + (size_t)sp * (kB * kH * kT);

    const int tid  = threadIdx.x;
    const int wave = tid >> 6;
    const int lane = tid & 63;
    const int l31  = lane & 31;
    const int grp  = lane >> 5;
    const int qw   = wave * 64;

    // Q B-fragments from global (rope + log2e/8 scale already applied)
    f16x8 aq[2][4];
    #pragma unroll
    for (int qg = 0; qg < 2; ++qg) {
        const _Float16* qrow = QKV + (size_t)(b * kT + q0 + qw + qg * 32 + l31) * kQKVN + h * 64 + grp * 8;
        #pragma unroll
        for (int c = 0; c < 4; ++c)
            aq[qg][c] = *reinterpret_cast<const f16x8*>(qrow + c * 16);
    }

    f32x16 Oacc[2][2] = {};
    float lsum[2] = { 0.f, 0.f };

    const int kr = tid >> 1, kc = (tid & 1) * 32;
    const int vr = tid >> 2, vc = (tid & 3) * 32;
    const _Float16* kg = QKV + (size_t)(b * kT + sp * 512 + kr) * kQKVN + 1024 + h * 64 + kc;
    const _Float16* vg = Vt + ((size_t)bh * 64 + vr) * (size_t)kT + sp * 512 + vc;

    for (int it = 0; it < 4; ++it) {
        {   // stage K tile [key][d] and Vt tile [d][key]
            #pragma unroll
            for (int j = 0; j < 32; j += 8) {
                *reinterpret_cast<f16x8*>(&Ks[kr * LDK + kc + j])  = *reinterpret_cast<const f16x8*>(kg + j);
                *reinterpret_cast<f16x8*>(&Vts[vr * LDV + vc + j]) = *reinterpret_cast<const f16x8*>(vg + j);
            }
            kg += (size_t)128 * kQKVN;
            vg += 128;
        }
        __syncthreads();

        #pragma unroll
        for (int kt = 0; kt < 4; ++kt) {
            f16x8 kf[4];
            #pragma unroll
            for (int c = 0; c < 4; ++c)
                kf[c] = *reinterpret_cast<const f16x8*>(&Ks[(kt * 32 + l31) * LDK + c * 16 + grp * 8]);

            f16x8 pfrag[2][2];
            #pragma unroll
            for (int qg = 0; qg < 2; ++qg) {
                f32x16 S = {};
                #pragma unroll
                for (int c = 0; c < 4; ++c)
                    S = __builtin_amdgcn_mfma_f32_32x32x16_f16(kf[c], aq[qg][c], S, 0, 0, 0);

                int q32[4][2];
                #pragma unroll
                for (int g = 0; g < 4; ++g) {
                    const float e0 = __builtin_amdgcn_exp2f(S[g * 4 + 0]);
                    const float e1 = __builtin_amdgcn_exp2f(S[g * 4 + 1]);
                    const float e2 = __builtin_amdgcn_exp2f(S[g * 4 + 2]);
                    const float e3 = __builtin_amdgcn_exp2f(S[g * 4 + 3]);
                    lsum[qg] += (e0 + e1) + (e2 + e3);
                    q32[g][0] = pkrtz_i(e0, e1);
                    q32[g][1] = pkrtz_i(e2, e3);
                }
                // asymmetric exchange: send exactly what the partner needs
                #pragma unroll
                for (int cl = 0; cl < 2; ++cl) {
                    const int s0 = grp ? q32[2 * cl][0] : q32[2 * cl + 1][0];
                    const int s1 = grp ? q32[2 * cl][1] : q32[2 * cl + 1][1];
                    const int r0 = __shfl_xor(s0, 32);
                    const int r1 = __shfl_xor(s1, 32);
                    union { int u[4]; f16x8 v; } pu;
                    pu.u[0] = grp ? r0 : q32[2 * cl][0];
                    pu.u[1] = grp ? r1 : q32[2 * cl][1];
                    pu.u[2] = grp ? q32[2 * cl + 1][0] : r0;
                    pu.u[3] = grp ? q32[2 * cl + 1][1] : r1;
                    pfrag[qg][cl] = pu.v;
                }
            }

            #pragma unroll
            for (int cl = 0; cl < 2; ++cl) {
                #pragma unroll
                for (int nt = 0; nt < 2; ++nt) {
                    f16x8 vf = *reinterpret_cast<const f16x8*>(
                        &Vts[(nt * 32 + l31) * LDV + kt * 32 + cl * 16 + grp * 8]);
                    Oacc[0][nt] = __builtin_amdgcn_mfma_f32_32x32x16_f16(pfrag[0][cl], vf, Oacc[0][nt], 0, 0, 0);
                    Oacc[1][nt] = __builtin_amdgcn_mfma_f32_32x32x16_f16(pfrag[1][cl], vf, Oacc[1][nt], 0, 0, 0);
                }
            }
        }
        __syncthreads();
    }

    // l partials
    lsum[0] += __shfl_xor(lsum[0], 32);
    lsum[1] += __shfl_xor(lsum[1], 32);
    if (grp == 0) {
        lpart[(size_t)bh * kT + q0 + qw + l31]      = lsum[0];
        lpart[(size_t)bh * kT + q0 + qw + 32 + l31] = lsum[1];
    }

    // unnormalized partial O (fp16), per-split stride
    #pragma unroll
    for (int qg = 0; qg < 2; ++qg)
        #pragma unroll
        for (int g = 0; g < 4; ++g)
            #pragma unroll
            for (int r = 0; r < 4; ++r) {
                const int reg = g * 4 + r;
                const int ql  = r + 8 * g + 4 * grp;
                const size_t orow = (size_t)(b * kT + q0 + qw + qg * 32 + ql);
                #pragma unroll
                for (int nt = 0; nt < 2; ++nt)
                    Opart[orow * ostride + h * 64 + nt * 32 + l31] = (_Float16)Oacc[qg][nt][reg];
            }
}

// ---------------------------------------------------------------------------
// Merge the 4 splits: Oh = (sum Op_s) / (sum l_s)
// ---------------------------------------------------------------------------
__global__ __launch_bounds__(256) void attn_reduce(const _Float16* __restrict__ Op0,
                                                   const _Float16* __restrict__ Op1,
                                                   const _Float16* __restrict__ Op2,
                                                   const _Float16* __restrict__ Op3,
                                                   const float* __restrict__ lp,
                                                   _Float16* __restrict__ Oh) {
    const int i = blockIdx.x * 256 + threadIdx.x;   // 1,048,576 threads x 8 halves
    const size_t base = (size_t)i * 8;
    const int row = (int)(base >> 10);
    const int col = (int)(base & 1023);
    const int b = row >> 11, t = row & 2047;
    const size_t lidx = ((size_t)(b * 16 + (col >> 6))) * kT + t;
    constexpr size_t lstr = (size_t)kB * kH * kT;
    const float linv = 1.0f / (lp[lidx] + lp[lstr + lidx] +
                               lp[2 * lstr + lidx] + lp[3 * lstr + lidx]);
    const f16x8 a0 = *reinterpret_cast<const f16x8*>(Op0 + base);
    const f16x8 a1 = *reinterpret_cast<const f16x8*>(Op1 + base);
    const f16x8 a2 = *reinterpret_cast<const f16x8*>(Op2 + (size_t)row * 3072 + col);
    const f16x8 a3 = *reinterpret_cast<const f16x8*>(Op3 + base);
    f16x8 o;
    #pragma unroll
    for (int j = 0; j < 8; ++j)
        o[j] = (_Float16)((((float)a0[j] + (float)a1[j]) +
                           ((float)a2[j] + (float)a3[j])) * linv);
    *reinterpret_cast<f16x8*>(Oh + base) = o;
}

// ---------------------------------------------------------------------------
extern "C" void kernel_launch(void* const* d_in, const int* in_sizes, int n_in,
                              void* d_out, int out_size, void* d_ws, size_t ws_size,
                              hipStream_t stream) {
    const float* x  = (const float*)d_in[0];
    const float* Wq = (const float*)d_in[1];
    const float* bq = (const float*)d_in[2];
    const float* Wk = (const float*)d_in[3];
    const float* bk = (const float*)d_in[4];
    const float* Wv = (const float*)d_in[5];
    const float* bv = (const float*)d_in[6];
    const float* Wo = (const float*)d_in[7];
    const float* bo = (const float*)d_in[8];
    float* out = (float*)d_out;

    char* ws = (char*)d_ws;
    _Float16* Xh    = (_Float16*)(ws);                         // 16 MB (-> Op0)
    _Float16* Wqkvh = (_Float16*)(ws + 16777216);              // 6 MB (-> lp[4])
    _Float16* Woh   = (_Float16*)(ws + 23068672);              // 2 MB
    float*    bqkv  = (float*)   (ws + 25165824);              // 16 KB
    _Float16* QKVh  = (_Float16*)(ws + 25182208);              // 48 MB
    _Float16* Vtb   = (_Float16*)(ws + 75513856);              // 16 MB
    _Float16* Ohb   = (_Float16*)(ws + 92291072);              // 16 MB (Op1 -> merged O)

    _Float16* Op0 = Xh;
    _Float16* Op2 = QKVh + 2048;          // dead V-columns, row stride 3072
    _Float16* Op3 = (_Float16*)d_out;     // first 16 MB of output buffer
    float*    lp  = (float*)(ws + 16777216);   // 4 x 512 KB in dead Wqkvh

    // casts + bias concat
    cast_all<<<12291, 256, 0, stream>>>(x, Wq, Wk, Wv, Wo, bq, bk, bv,
                                        Xh, Wqkvh, Woh, bqkv);

    // fused QKV projection with RoPE epilogue (XCD-swizzled 1D grid, 1536 blocks)
    gemm_f16<_Float16, true><<<1536, 256, 0, stream>>>(
        Xh, Wqkvh, bqkv, QKVh, kBT, kQKVN, kD);

    // V -> Vt[bh][d][t]
    transpose_v<<<dim3(kT / 64, kB * kH), 256, 0, stream>>>(QKVh, Vtb);

    // split-K flash attention (S=4), swizzled 1D grid -> partials
    attn_mfma<<<2048, 256, 0, stream>>>(QKVh, Vtb, Op0, Ohb, Op2, Op3, lp);

    // merge splits -> Ohb (normalized fp16)
    attn_reduce<<<(kBT * kD) / (8 * 256), 256, 0, stream>>>(
        Op0, Ohb, Op2, Op3, lp, Ohb);

    // output projection (fp32 out, XCD-swizzled 1D grid, 512 blocks)
    gemm_f16<float, false><<<512, 256, 0, stream>>>(
        Ohb, Woh, bo, out, kBT, kD, kD);
}

// Round 10
// 325.195 us; speedup vs baseline: 1.0324x; 1.0324x over previous
//
#include <hip/hip_runtime.h>
#include <cstddef>
#include <cstdint>

// Problem constants
constexpr int kB   = 4;
constexpr int kT   = 2048;
constexpr int kD   = 1024;   // d_model
constexpr int kH   = 16;     // heads
constexpr int kDh  = 64;     // head dim
constexpr int kBT  = kB * kT;          // 8192 rows
constexpr int kQKVN = 3 * kD;          // 3072

typedef _Float16 f16x8 __attribute__((ext_vector_type(8)));
typedef _Float16 f16x4 __attribute__((ext_vector_type(4)));
typedef _Float16 f16x2 __attribute__((ext_vector_type(2)));
typedef float    f32x4  __attribute__((ext_vector_type(4)));
typedef float    f32x16 __attribute__((ext_vector_type(16)));

#define GLD16(g, l)                                                        \
    __builtin_amdgcn_global_load_lds(                                      \
        (const __attribute__((address_space(1))) void*)(g),                \
        (__attribute__((address_space(3))) void*)(l), 16, 0, 0)

static __device__ __forceinline__ int pkrtz_i(float a, float b) {
    auto t = __builtin_amdgcn_cvt_pkrtz(a, b);   // v_cvt_pkrtz_f16_f32
    return *reinterpret_cast<int*>(&t);
}

// ---------------------------------------------------------------------------
// all fp32->fp16 casts + bias concat in one dispatch
// ---------------------------------------------------------------------------
__global__ __launch_bounds__(256) void cast_all(const float* __restrict__ x,
                                                const float* __restrict__ Wq,
                                                const float* __restrict__ Wk,
                                                const float* __restrict__ Wv,
                                                const float* __restrict__ Wo,
                                                const float* __restrict__ bq,
                                                const float* __restrict__ bk,
                                                const float* __restrict__ bv,
                                                _Float16* __restrict__ Xh,
                                                _Float16* __restrict__ Wqkvh,
                                                _Float16* __restrict__ Woh,
                                                float* __restrict__ bqkv) {
    const int i = blockIdx.x * 256 + threadIdx.x;
    if (i >= 3145728) {                 // bias concat: 768 float4 groups
        const int j = i - 3145728;
        if (j < 768) {
            const float* bs = (j < 256) ? bq : (j < 512 ? bk : bv);
            const int jo = j & 255;
            reinterpret_cast<float4*>(bqkv)[j] =
                reinterpret_cast<const float4*>(bs)[jo];
        }
        return;
    }
    const float* src; _Float16* dst; int off;
    if (i < 2097152)      { src = x;  dst = Xh;              off = i; }
    else if (i < 2359296) { src = Wq; dst = Wqkvh;           off = i - 2097152; }
    else if (i < 2621440) { src = Wk; dst = Wqkvh + 1048576; off = i - 2359296; }
    else if (i < 2883584) { src = Wv; dst = Wqkvh + 2097152; off = i - 2621440; }
    else                  { src = Wo; dst = Woh;             off = i - 2883584; }
    const float4 v = reinterpret_cast<const float4*>(src)[off];
    f16x4 o = { (_Float16)v.x, (_Float16)v.y, (_Float16)v.z, (_Float16)v.w };
    reinterpret_cast<f16x4*>(dst)[off] = o;
}

// ---------------------------------------------------------------------------
// fp16 MFMA GEMM (QKV projection): C[M,N] = A[M,K] @ B[N,K]^T + bias
// BK=64 staged as two 32-K chunks in separate LDS regions (GLD16-compatible).
// 2D grid (default dispatch order — R9's 1D swizzle regressed A-locality).
// RoPE fused in the epilogue for cols<2048 (pair partner is lane^1); Q half
// pre-scaled by log2(e)/8 for the max-free exp2 softmax.
// ---------------------------------------------------------------------------
__global__ __launch_bounds__(256) void gemm_qkv(const _Float16* __restrict__ A,
                                                const _Float16* __restrict__ B,
                                                const float* __restrict__ bias,
                                                _Float16* __restrict__ C,
                                                int M, int N, int K) {
    constexpr int BK = 64;
    __shared__ _Float16 As[128 * BK];   // [ko][128][32] chunked
    __shared__ _Float16 Bs[128 * BK];

    const int tid  = threadIdx.x;
    const int wave = tid >> 6;
    const int lane = tid & 63;
    const int quad = lane >> 4;
    const int r16  = lane & 15;
    const int m0 = blockIdx.x * 128;
    const int n0 = blockIdx.y * 128;

    const int srow = lane >> 2;
    const int scol = (lane & 3) * 8;
    const _Float16* Ag0 = A + (size_t)(m0 + wave * 16 + srow) * K + scol;
    const _Float16* Ag1 = A + (size_t)(m0 + 64 + wave * 16 + srow) * K + scol;
    const _Float16* Bg0 = B + (size_t)(n0 + wave * 16 + srow) * K + scol;
    const _Float16* Bg1 = B + (size_t)(n0 + 64 + wave * 16 + srow) * K + scol;
    _Float16* Al0 = &As[(size_t)wave * 512];
    _Float16* Al1 = &As[(size_t)(wave + 4) * 512];
    _Float16* Bl0 = &Bs[(size_t)wave * 512];
    _Float16* Bl1 = &Bs[(size_t)(wave + 4) * 512];

    const int wm = (wave & 1) * 64;
    const int wn = (wave >> 1) * 64;

    f32x4 acc[4][4] = {};

    for (int k0 = 0; k0 < K; k0 += BK) {
        GLD16(Ag0 + k0,      Al0);
        GLD16(Ag1 + k0,      Al1);
        GLD16(Ag0 + k0 + 32, Al0 + 4096);
        GLD16(Ag1 + k0 + 32, Al1 + 4096);
        GLD16(Bg0 + k0,      Bl0);
        GLD16(Bg1 + k0,      Bl1);
        GLD16(Bg0 + k0 + 32, Bl0 + 4096);
        GLD16(Bg1 + k0 + 32, Bl1 + 4096);
        __syncthreads();

        #pragma unroll
        for (int ko = 0; ko < 2; ++ko) {
            f16x8 a[4], bf[4];
            #pragma unroll
            for (int mi = 0; mi < 4; ++mi)
                a[mi] = *reinterpret_cast<const f16x8*>(
                    &As[ko * 4096 + (wm + mi * 16 + r16) * 32 + quad * 8]);
            #pragma unroll
            for (int ni = 0; ni < 4; ++ni)
                bf[ni] = *reinterpret_cast<const f16x8*>(
                    &Bs[ko * 4096 + (wn + ni * 16 + r16) * 32 + quad * 8]);
            #pragma unroll
            for (int mi = 0; mi < 4; ++mi)
                #pragma unroll
                for (int ni = 0; ni < 4; ++ni)
                    acc[mi][ni] = __builtin_amdgcn_mfma_f32_16x16x32_f16(a[mi], bf[ni], acc[mi][ni], 0, 0, 0);
        }
        __syncthreads();
    }

    #pragma unroll
    for (int mi = 0; mi < 4; ++mi) {
        #pragma unroll
        for (int ni = 0; ni < 4; ++ni) {
            const int col = n0 + wn + ni * 16 + r16;
            const float bv = bias[col];
            #pragma unroll
            for (int r = 0; r < 4; ++r) {
                const int row = m0 + wm + mi * 16 + quad * 4 + r;
                float v = acc[mi][ni][r] + bv;
                // pair partner (col^1) lives in lane^1, same (mi,ni,r)
                const float vx = __shfl_xor(v, 1);
                if (col < 2048) {
                    const int t = row & (kT - 1);
                    const int p = (col & 63) >> 1;
                    const float rev = (float)t * ((float)p *
                        (1.0e-4f * 0.15915494309189535f));
                    const float s = __builtin_amdgcn_sinf(rev);
                    const float c = __builtin_amdgcn_cosf(rev);
                    const float sgn = (r16 & 1) ? s : -s;  // even: -s*partner
                    v = v * c + vx * sgn;
                    if (col < 1024) v *= 0.18033688011112443f;  // log2e/8
                }
                C[(size_t)row * N + col] = (_Float16)v;
            }
        }
    }
}

// ---------------------------------------------------------------------------
// Out projection with FUSED split-merge + normalization in the A-staging:
// A_norm[row][k] = (Op0[row][k] + Op1[row][k]) / (l0[row,h] + l1[row,h]),
// h = k>>6 (each thread's 32-col staging chunk lies within one head).
// B staged via GLD16 as usual. C written fp32.
// ---------------------------------------------------------------------------
__global__ __launch_bounds__(256) void gemm_out_fused(
        const _Float16* __restrict__ Op0,
        const _Float16* __restrict__ Op1,
        const float* __restrict__ lp,
        const _Float16* __restrict__ B,
        const float* __restrict__ bias,
        float* __restrict__ C) {
    constexpr int K = 1024, N = 1024, BK = 64;
    __shared__ _Float16 As[128 * BK];   // [ko][128][32] chunked
    __shared__ _Float16 Bs[128 * BK];

    const int tid  = threadIdx.x;
    const int wave = tid >> 6;
    const int lane = tid & 63;
    const int quad = lane >> 4;
    const int r16  = lane & 15;
    const int m0 = blockIdx.x * 128;
    const int n0 = blockIdx.y * 128;

    // B staging (GLD16)
    const int srow = lane >> 2;
    const int scol = (lane & 3) * 8;
    const _Float16* Bg0 = B + (size_t)(n0 + wave * 16 + srow) * K + scol;
    const _Float16* Bg1 = B + (size_t)(n0 + 64 + wave * 16 + srow) * K + scol;
    _Float16* Bl0 = &Bs[(size_t)wave * 512];
    _Float16* Bl1 = &Bs[(size_t)(wave + 4) * 512];

    // A fused staging: thread covers row m0+(tid>>1), 32 cols at (tid&1)*32
    const int arow = tid >> 1;
    const int ko_s = tid & 1;
    const int row  = m0 + arow;
    const int bb   = row >> 11, tt = row & 2047;
    const size_t abase = (size_t)row * K + ko_s * 32;
    constexpr size_t lstr = (size_t)kB * kH * kT;

    const int wm = (wave & 1) * 64;
    const int wn = (wave >> 1) * 64;

    f32x4 acc[4][4] = {};

    for (int k0 = 0; k0 < K; k0 += BK) {
        GLD16(Bg0 + k0,      Bl0);
        GLD16(Bg1 + k0,      Bl1);
        GLD16(Bg0 + k0 + 32, Bl0 + 4096);
        GLD16(Bg1 + k0 + 32, Bl1 + 4096);

        // A: load partials, merge + normalize, write LDS
        {
            const int h = k0 >> 6;   // iter-uniform head
            const size_t lidx = (size_t)(bb * 16 + h) * 2048 + tt;
            const float linv = 1.0f / (lp[lidx] + lp[lstr + lidx]);
            const _Float16 lh = (_Float16)linv;
            #pragma unroll
            for (int j = 0; j < 4; ++j) {
                f16x8 a0 = *reinterpret_cast<const f16x8*>(Op0 + abase + k0 + 8 * j);
                f16x8 a1 = *reinterpret_cast<const f16x8*>(Op1 + abase + k0 + 8 * j);
                f16x8 s = (a0 + a1) * lh;     // v_pk_add_f16 / v_pk_mul_f16
                *reinterpret_cast<f16x8*>(&As[ko_s * 4096 + arow * 32 + 8 * j]) = s;
            }
        }
        __syncthreads();

        #pragma unroll
        for (int ko = 0; ko < 2; ++ko) {
            f16x8 a[4], bf[4];
            #pragma unroll
            for (int mi = 0; mi < 4; ++mi)
                a[mi] = *reinterpret_cast<const f16x8*>(
                    &As[ko * 4096 + (wm + mi * 16 + r16) * 32 + quad * 8]);
            #pragma unroll
            for (int ni = 0; ni < 4; ++ni)
                bf[ni] = *reinterpret_cast<const f16x8*>(
                    &Bs[ko * 4096 + (wn + ni * 16 + r16) * 32 + quad * 8]);
            #pragma unroll
            for (int mi = 0; mi < 4; ++mi)
                #pragma unroll
                for (int ni = 0; ni < 4; ++ni)
                    acc[mi][ni] = __builtin_amdgcn_mfma_f32_16x16x32_f16(a[mi], bf[ni], acc[mi][ni], 0, 0, 0);
        }
        __syncthreads();
    }

    #pragma unroll
    for (int mi = 0; mi < 4; ++mi) {
        #pragma unroll
        for (int ni = 0; ni < 4; ++ni) {
            const int col = n0 + wn + ni * 16 + r16;
            const float bv = bias[col];
            #pragma unroll
            for (int r = 0; r < 4; ++r) {
                const int row2 = m0 + wm + mi * 16 + quad * 4 + r;
                C[(size_t)row2 * N + col] = acc[mi][ni][r] + bv;
            }
        }
    }
}

// ---------------------------------------------------------------------------
// V transpose: QKV[,2048+h*64+d] (rows t) -> Vt[bh][d][t]
// ---------------------------------------------------------------------------
__global__ __launch_bounds__(256) void transpose_v(const _Float16* __restrict__ QKV,
                                                   _Float16* __restrict__ Vt) {
    const int bh = blockIdx.y;
    const int t0 = blockIdx.x * 64;
    const int b = bh >> 4, h = bh & 15;
    __shared__ _Float16 T[64 * 72];

    const int tid = threadIdx.x;
    const int r   = tid >> 2;
    const int c0  = (tid & 3) * 16;
    const _Float16* src = QKV + (size_t)(b * kT + t0 + r) * kQKVN + 2048 + h * 64 + c0;
    *reinterpret_cast<f16x8*>(&T[r * 72 + c0])     = *reinterpret_cast<const f16x8*>(src);
    *reinterpret_cast<f16x8*>(&T[r * 72 + c0 + 8]) = *reinterpret_cast<const f16x8*>(src + 8);
    __syncthreads();

    const int d = tid >> 2, tc0 = (tid & 3) * 16;
    f16x8 o0, o1;
    #pragma unroll
    for (int j = 0; j < 8; ++j) o0[j] = T[(tc0 + j) * 72 + d];
    #pragma unroll
    for (int j = 0; j < 8; ++j) o1[j] = T[(tc0 + 8 + j) * 72 + d];
    _Float16* dst = Vt + ((size_t)bh * 64 + d) * kT + t0 + tc0;
    *reinterpret_cast<f16x8*>(dst)     = o0;
    *reinterpret_cast<f16x8*>(dst + 8) = o1;
}

// ---------------------------------------------------------------------------
// Flash attention, split-K (S=2), XCD-locality swizzled 1D grid (1024 blocks):
//   id = qt*8 + (pair&7) + (pair>>3)*64, pair = bh*2+sp -> the 8 q-tile blocks
//   sharing one (bh,sp)'s 256 KB of K/V get IDs congruent mod 8 -> same XCD
//   -> K/V staging re-reads hit that XCD's L2 (R8/R9-verified, FETCH 164->49).
// Each block: 1024 keys in 8 tiles of 128. Max-free softmax => splits merge
// LINEARLY (O = sum O_s, l = sum l_s); merge happens inside gemm_out_fused.
// P C->A transform via asymmetric shfl_xor(32) quad exchange.
// C/D layout: col = lane&31, row = (reg&3) + 8*(reg>>2) + 4*(lane>>5).
// A/B frag: row/col = lane&31, k = (lane>>5)*8 + j.  [HW-verified R3-R9]
// ---------------------------------------------------------------------------
__global__ __launch_bounds__(256) void attn_mfma(const _Float16* __restrict__ QKV,
                                                 const _Float16* __restrict__ Vt,
                                                 _Float16* __restrict__ Op0,
                                                 _Float16* __restrict__ Op1,
                                                 float* __restrict__ lp) {
    constexpr int LDK = 72, LDV = 136;
    __shared__ _Float16 Ks[128 * LDK];   // [key 0..128)[d 0..64)
    __shared__ _Float16 Vts[64 * LDV];   // [d 0..64)[key 0..128)

    // swizzled decode
    const int id   = blockIdx.x;              // 0..1023
    const int qt   = (id >> 3) & 7;
    const int pair = ((id >> 6) << 3) + (id & 7);   // 0..127
    const int bh = pair >> 1;
    const int sp = pair & 1;
    const int b = bh >> 4, h = bh & 15;
    const int q0 = qt * 256;

    _Float16* __restrict__ Opart = sp ? Op1 : Op0;
    float* __restrict__ lpart = lp + (size_t)sp * (kB * kH * kT);

    const int tid  = threadIdx.x;
    const int wave = tid >> 6;
    const int lane = tid & 63;
    const int l31  = lane & 31;
    const int grp  = lane >> 5;
    const int qw   = wave * 64;

    // Q B-fragments from global (rope + log2e/8 scale already applied)
    f16x8 aq[2][4];
    #pragma unroll
    for (int qg = 0; qg < 2; ++qg) {
        const _Float16* qrow = QKV + (size_t)(b * kT + q0 + qw + qg * 32 + l31) * kQKVN + h * 64 + grp * 8;
        #pragma unroll
        for (int c = 0; c < 4; ++c)
            aq[qg][c] = *reinterpret_cast<const f16x8*>(qrow + c * 16);
    }

    f32x16 Oacc[2][2] = {};
    float lsum[2] = { 0.f, 0.f };

    const int kr = tid >> 1, kc = (tid & 1) * 32;
    const int vr = tid >> 2, vc = (tid & 3) * 32;
    const _Float16* kg = QKV + (size_t)(b * kT + sp * 1024 + kr) * kQKVN + 1024 + h * 64 + kc;
    const _Float16* vg = Vt + ((size_t)bh * 64 + vr) * (size_t)kT + sp * 1024 + vc;

    for (int it = 0; it < 8; ++it) {
        {   // stage K tile [key][d] and Vt tile [d][key]
            #pragma unroll
            for (int j = 0; j < 32; j += 8) {
                *reinterpret_cast<f16x8*>(&Ks[kr * LDK + kc + j])  = *reinterpret_cast<const f16x8*>(kg + j);
                *reinterpret_cast<f16x8*>(&Vts[vr * LDV + vc + j]) = *reinterpret_cast<const f16x8*>(vg + j);
            }
            kg += (size_t)128 * kQKVN;
            vg += 128;
        }
        __syncthreads();

        #pragma unroll
        for (int kt = 0; kt < 4; ++kt) {
            f16x8 kf[4];
            #pragma unroll
            for (int c = 0; c < 4; ++c)
                kf[c] = *reinterpret_cast<const f16x8*>(&Ks[(kt * 32 + l31) * LDK + c * 16 + grp * 8]);

            f16x8 pfrag[2][2];
            #pragma unroll
            for (int qg = 0; qg < 2; ++qg) {
                f32x16 S = {};
                #pragma unroll
                for (int c = 0; c < 4; ++c)
                    S = __builtin_amdgcn_mfma_f32_32x32x16_f16(kf[c], aq[qg][c], S, 0, 0, 0);

                int q32[4][2];
                #pragma unroll
                for (int g = 0; g < 4; ++g) {
                    const float e0 = __builtin_amdgcn_exp2f(S[g * 4 + 0]);
                    const float e1 = __builtin_amdgcn_exp2f(S[g * 4 + 1]);
                    const float e2 = __builtin_amdgcn_exp2f(S[g * 4 + 2]);
                    const float e3 = __builtin_amdgcn_exp2f(S[g * 4 + 3]);
                    lsum[qg] += (e0 + e1) + (e2 + e3);
                    q32[g][0] = pkrtz_i(e0, e1);
                    q32[g][1] = pkrtz_i(e2, e3);
                }
                // asymmetric exchange: send exactly what the partner needs
                #pragma unroll
                for (int cl = 0; cl < 2; ++cl) {
                    const int s0 = grp ? q32[2 * cl][0] : q32[2 * cl + 1][0];
                    const int s1 = grp ? q32[2 * cl][1] : q32[2 * cl + 1][1];
                    const int r0 = __shfl_xor(s0, 32);
                    const int r1 = __shfl_xor(s1, 32);
                    union { int u[4]; f16x8 v; } pu;
                    pu.u[0] = grp ? r0 : q32[2 * cl][0];
                    pu.u[1] = grp ? r1 : q32[2 * cl][1];
                    pu.u[2] = grp ? q32[2 * cl + 1][0] : r0;
                    pu.u[3] = grp ? q32[2 * cl + 1][1] : r1;
                    pfrag[qg][cl] = pu.v;
                }
            }

            #pragma unroll
            for (int cl = 0; cl < 2; ++cl) {
                #pragma unroll
                for (int nt = 0; nt < 2; ++nt) {
                    f16x8 vf = *reinterpret_cast<const f16x8*>(
                        &Vts[(nt * 32 + l31) * LDV + kt * 32 + cl * 16 + grp * 8]);
                    Oacc[0][nt] = __builtin_amdgcn_mfma_f32_32x32x16_f16(pfrag[0][cl], vf, Oacc[0][nt], 0, 0, 0);
                    Oacc[1][nt] = __builtin_amdgcn_mfma_f32_32x32x16_f16(pfrag[1][cl], vf, Oacc[1][nt], 0, 0, 0);
                }
            }
        }
        __syncthreads();
    }

    // l partials
    lsum[0] += __shfl_xor(lsum[0], 32);
    lsum[1] += __shfl_xor(lsum[1], 32);
    if (grp == 0) {
        lpart[(size_t)bh * kT + q0 + qw + l31]      = lsum[0];
        lpart[(size_t)bh * kT + q0 + qw + 32 + l31] = lsum[1];
    }

    // unnormalized partial O (fp16)
    #pragma unroll
    for (int qg = 0; qg < 2; ++qg)
        #pragma unroll
        for (int g = 0; g < 4; ++g)
            #pragma unroll
            for (int r = 0; r < 4; ++r) {
                const int reg = g * 4 + r;
                const int ql  = r + 8 * g + 4 * grp;
                const size_t orow = (size_t)(b * kT + q0 + qw + qg * 32 + ql);
                #pragma unroll
                for (int nt = 0; nt < 2; ++nt)
                    Opart[orow * kD + h * 64 + nt * 32 + l31] = (_Float16)Oacc[qg][nt][reg];
            }
}

// ---------------------------------------------------------------------------
extern "C" void kernel_launch(void* const* d_in, const int* in_sizes, int n_in,
                              void* d_out, int out_size, void* d_ws, size_t ws_size,
                              hipStream_t stream) {
    const float* x  = (const float*)d_in[0];
    const float* Wq = (const float*)d_in[1];
    const float* bq = (const float*)d_in[2];
    const float* Wk = (const float*)d_in[3];
    const float* bk = (const float*)d_in[4];
    const float* Wv = (const float*)d_in[5];
    const float* bv = (const float*)d_in[6];
    const float* Wo = (const float*)d_in[7];
    const float* bo = (const float*)d_in[8];
    float* out = (float*)d_out;

    char* ws = (char*)d_ws;
    _Float16* Xh    = (_Float16*)(ws);                         // 16 MB (-> Op0)
    _Float16* Wqkvh = (_Float16*)(ws + 16777216);              // 6 MB (-> lp[2])
    _Float16* Woh   = (_Float16*)(ws + 23068672);              // 2 MB
    float*    bqkv  = (float*)   (ws + 25165824);              // 16 KB
    _Float16* QKVh  = (_Float16*)(ws + 25182208);              // 48 MB
    _Float16* Vtb   = (_Float16*)(ws + 75513856);              // 16 MB
    _Float16* Ohb   = (_Float16*)(ws + 92291072);              // 16 MB (-> Op1)

    _Float16* Op0 = Xh;                        // dead after QKV GEMM
    _Float16* Op1 = Ohb;
    float*    lp  = (float*)(ws + 16777216);   // 2 x 512 KB in dead Wqkvh

    // casts + bias concat
    cast_all<<<12291, 256, 0, stream>>>(x, Wq, Wk, Wv, Wo, bq, bk, bv,
                                        Xh, Wqkvh, Woh, bqkv);

    // fused QKV projection with RoPE epilogue (2D grid)
    gemm_qkv<<<dim3(kBT / 128, kQKVN / 128), 256, 0, stream>>>(
        Xh, Wqkvh, bqkv, QKVh, kBT, kQKVN, kD);

    // V -> Vt[bh][d][t]
    transpose_v<<<dim3(kT / 64, kB * kH), 256, 0, stream>>>(QKVh, Vtb);

    // split-K flash attention (S=2), swizzled 1D grid -> partials
    attn_mfma<<<1024, 256, 0, stream>>>(QKVh, Vtb, Op0, Op1, lp);

    // output projection with fused split-merge + normalization (fp32 out)
    gemm_out_fused<<<dim3(kBT / 128, kD / 128), 256, 0, stream>>>(
        Op0, Op1, lp, Woh, bo, out);
}